// Round 19
// baseline (550.609 us; speedup 1.0000x reference)
//
#include <hip/hip_runtime.h>
#include <hip/hip_bf16.h>
#include <cstddef>

#define NND 50000
#define NNDP 50048    // padded: multiple of 64
#define NED 400000
#define NEDP 400128   // padded: multiple of 96 (and 64)
#define HD 128
#define NSTEP 3
#define NSB 196       // scan blocks: 196*256 >= NNDP
#define NWP 32

using u16 = unsigned short;
typedef __attribute__((ext_vector_type(8))) short bf16x8;
typedef __attribute__((ext_vector_type(4))) float f32x4;

__device__ __forceinline__ u16 f2b(float f) {
    __hip_bfloat16 b = __float2bfloat16(f);
    union { __hip_bfloat16 b; u16 u; } v; v.b = b;
    return v.u;
}
__device__ __forceinline__ float b2f(u16 u) {
    union { unsigned u; float f; } v; v.u = ((unsigned)u) << 16;
    return v.f;
}

// bijective XCD-chunked swizzle (m204)
__device__ __forceinline__ int xcd_swz(int orig, int nwg) {
    int q = nwg >> 3, r = nwg & 7;
    int xcd = orig & 7, idx = orig >> 3;
    return (xcd < r ? xcd * (q + 1) : r * (q + 1) + (xcd - r) * q) + idx;
}

template <int RT>
__device__ __forceinline__ void zero_accs(f32x4 (&acc)[RT][4]) {
    #pragma unroll
    for (int g = 0; g < RT; g++)
        #pragma unroll
        for (int i = 0; i < 4; i++) acc[g][i] = (f32x4)(0.0f);
}

// Transposed-C: D = mfma(A=W_frag, B=act_frag); C/D: lane&15 <-> data-row,
// (lane>>4)*4+i <-> out-CHANNEL (4 consecutive channels per lane per ct).
__device__ __forceinline__ void mfma4T(bf16x8 act, const bf16x8 (&wf)[4], f32x4 (&accr)[4]) {
    accr[0] = __builtin_amdgcn_mfma_f32_16x16x32_bf16(wf[0], act, accr[0], 0, 0, 0);
    accr[1] = __builtin_amdgcn_mfma_f32_16x16x32_bf16(wf[1], act, accr[1], 0, 0, 0);
    accr[2] = __builtin_amdgcn_mfma_f32_16x16x32_bf16(wf[2], act, accr[2], 0, 0, 0);
    accr[3] = __builtin_amdgcn_mfma_f32_16x16x32_bf16(wf[3], act, accr[3], 0, 0, 0);
}

// Preload a K=128 layer's 16 weight fragments into registers.
__device__ __forceinline__ void load_w16(const u16* __restrict__ Wf, int wc, int lane,
                                         bf16x8 (&wB)[16]) {
    const u16* bp = Wf + (size_t)(wc * 16) * 512 + lane * 8;
    #pragma unroll
    for (int i = 0; i < 16; i++) wB[i] = *(const bf16x8*)(bp + i * 512);
}

// K=128 layer with REGISTER-resident weights; act rows from LDS t (stride 136).
template <int RT>
__device__ __forceinline__ void gemm_reg_T(const u16* t, int rbase, const bf16x8 (&wB)[16],
                                           int lane, f32x4 (&acc)[RT][4]) {
    const int cl = lane & 15, q8 = (lane >> 4) * 8;
    #pragma unroll
    for (int k0 = 0; k0 < 4; k0++) {
        const bf16x8 wf[4] = {wB[k0], wB[4 + k0], wB[8 + k0], wB[12 + k0]};
        #pragma unroll
        for (int rt = 0; rt < RT; rt++) {
            bf16x8 a = *(const bf16x8*)(t + (rbase + rt * 16 + cl) * 136 + k0 * 32 + q8);
            mfma4T(a, wf, acc[rt]);
        }
    }
}

// K = KC*32 layer, act rows from LDS t (stride 136), weights fragment-major (global).
template <int KC, int RT>
__device__ __forceinline__ void gemm_lds_T(const u16* t, int rbase,
                                           const u16* __restrict__ Wf,
                                           int wc, int lane, f32x4 (&acc)[RT][4]) {
    const int cl = lane & 15, q8 = (lane >> 4) * 8;
    const u16* bp = Wf + (size_t)(wc * 4 * KC) * 512 + lane * 8;
    #pragma unroll
    for (int k0 = 0; k0 < KC; k0++) {
        bf16x8 wf[4];
        #pragma unroll
        for (int ct = 0; ct < 4; ct++) wf[ct] = *(const bf16x8*)(bp + (ct * KC + k0) * 512);
        #pragma unroll
        for (int rt = 0; rt < RT; rt++) {
            bf16x8 a = *(const bf16x8*)(t + (rbase + rt * 16 + cl) * 136 + k0 * 32 + q8);
            mfma4T(a, wf, acc[rt]);
        }
    }
}

// Store transposed-C tile to LDS: one ds_write_b64 per (rt,ct).
template <int RT, bool RELU>
__device__ __forceinline__ void store_T(u16* T, int rbase, int wc, int lane,
        const f32x4 (&acc)[RT][4], const float* __restrict__ bias) {
    const int cl = lane & 15, q = lane >> 4;
    float4 bv[4];
    #pragma unroll
    for (int ct = 0; ct < 4; ct++)
        bv[ct] = *(const float4*)(bias + wc * 64 + ct * 16 + q * 4);
    #pragma unroll
    for (int rt = 0; rt < RT; rt++) {
        const int row = rbase + rt * 16 + cl;
        #pragma unroll
        for (int ct = 0; ct < 4; ct++) {
            float v0 = acc[rt][ct][0] + bv[ct].x;
            float v1 = acc[rt][ct][1] + bv[ct].y;
            float v2 = acc[rt][ct][2] + bv[ct].z;
            float v3 = acc[rt][ct][3] + bv[ct].w;
            if (RELU) {
                v0 = fmaxf(v0, 0.f); v1 = fmaxf(v1, 0.f);
                v2 = fmaxf(v2, 0.f); v3 = fmaxf(v3, 0.f);
            }
            uint2 pk;
            pk.x = (unsigned)f2b(v0) | ((unsigned)f2b(v1) << 16);
            pk.y = (unsigned)f2b(v2) | ((unsigned)f2b(v3) << 16);
            *(uint2*)(T + row * 136 + wc * 64 + ct * 16 + q * 4) = pk;
        }
    }
}

// store_T without bias/relu, PERMUTED column: colp = wc*64 + q*16 + ct*4.
template <int RT>
__device__ __forceinline__ void store_T_perm(u16* T, int rbase, int wc, int lane,
        const f32x4 (&acc)[RT][4]) {
    const int cl = lane & 15, q = lane >> 4;
    #pragma unroll
    for (int rt = 0; rt < RT; rt++) {
        const int row = rbase + rt * 16 + cl;
        #pragma unroll
        for (int ct = 0; ct < 4; ct++) {
            uint2 pk;
            pk.x = (unsigned)f2b(acc[rt][ct][0]) | ((unsigned)f2b(acc[rt][ct][1]) << 16);
            pk.y = (unsigned)f2b(acc[rt][ct][2]) | ((unsigned)f2b(acc[rt][ct][3]) << 16);
            *(uint2*)(T + row * 136 + wc * 64 + q * 16 + ct * 4) = pk;
        }
    }
}

// Coalesced wave-private epilogue: plain copy.
template <int RT>
__device__ __forceinline__ void epi_plain(const u16* T, u16* __restrict__ base, int row0,
        int rbase, int nrows, int wc, int lane) {
    #pragma unroll
    for (int p = 0; p < RT * 2; p++) {
        const int lrow = rbase + p * 8 + (lane >> 3);
        const int col = wc * 64 + (lane & 7) * 8;
        const int grow = row0 + lrow;
        if (grow < nrows) {
            bf16x8 tv = *(const bf16x8*)(T + lrow * 136 + col);
            *(bf16x8*)(base + (size_t)grow * HD + col) = tv;
        }
    }
}

// ---------------- CSR build (hierarchical scan, all parallel) ----------------
__global__ void count_kernel(const int* __restrict__ eidx, int* __restrict__ counts) {
    int i = blockIdx.x * 256 + threadIdx.x;
    if (i < NED) atomicAdd(&counts[eidx[NED + i]], 1);
}

__global__ __launch_bounds__(256) void bsum_kernel(const int* __restrict__ counts,
                                                   int* __restrict__ bsum) {
    __shared__ int sm[256];
    const int i = threadIdx.x, b = blockIdx.x;
    const int idx = b * 256 + i;
    sm[i] = (idx < NNDP) ? counts[idx] : 0;
    __syncthreads();
    for (int ofs = 128; ofs > 0; ofs >>= 1) {
        if (i < ofs) sm[i] += sm[i + ofs];
        __syncthreads();
    }
    if (i == 0) bsum[b] = sm[0];
}

__global__ __launch_bounds__(256) void bscan_kernel(const int* __restrict__ bsum,
                                                    int* __restrict__ bbase,
                                                    int* __restrict__ offsets) {
    __shared__ int sm[256];
    const int i = threadIdx.x;
    int v = (i < NSB) ? bsum[i] : 0;
    sm[i] = v;
    __syncthreads();
    for (int ofs = 1; ofs < 256; ofs <<= 1) {
        int t = (i >= ofs) ? sm[i - ofs] : 0;
        __syncthreads();
        sm[i] += t;
        __syncthreads();
    }
    if (i < NSB) bbase[i] = sm[i] - v;
    if (i == NSB - 1) offsets[NNDP] = sm[i];
}

__global__ __launch_bounds__(256) void blocal_kernel(const int* __restrict__ counts,
                                                     const int* __restrict__ bbase,
                                                     int* __restrict__ offsets,
                                                     int* __restrict__ cursors) {
    __shared__ int sm[256];
    const int i = threadIdx.x, b = blockIdx.x;
    const int idx = b * 256 + i;
    int v = (idx < NNDP) ? counts[idx] : 0;
    sm[i] = v;
    __syncthreads();
    for (int ofs = 1; ofs < 256; ofs <<= 1) {
        int t = (i >= ofs) ? sm[i - ofs] : 0;
        __syncthreads();
        sm[i] += t;
        __syncthreads();
    }
    if (idx < NNDP) {
        int excl = sm[i] - v + bbase[b];
        offsets[idx] = excl;
        cursors[idx] = excl;
    }
}

__global__ void fill_kernel(const int* __restrict__ eidx, int* __restrict__ cursors,
                            int4* __restrict__ epk) {
    int i = blockIdx.x * 256 + threadIdx.x;
    if (i >= NED) return;
    int d = eidx[NED + i];
    int pos = atomicAdd(&cursors[d], 1);
    int4 v; v.x = eidx[i]; v.y = d; v.z = i; v.w = 0;
    epk[pos] = v;
}

// ---------------- fused weight prep ----------------
struct WPall {
    const float* s[NWP];
    u16* d[NWP];
    int K[NWP];
    int Kp[NWP];
};

__global__ void wprep_all(WPall a) {
    const int wi = blockIdx.y;
    const int Kp = a.Kp[wi];
    int idx = blockIdx.x * 256 + threadIdx.x;
    if (idx >= 128 * Kp) return;
    const int K = a.K[wi];
    const float* __restrict__ src = a.s[wi];
    int j = idx & 7, lane = (idx >> 3) & 63, rest = idx >> 9;
    int KC = Kp >> 5;
    int k0 = rest % KC, n0 = rest / KC;
    int n = n0 * 16 + (lane & 15);
    int k = k0 * 32 + (lane >> 4) * 8 + j;
    float v = (k < K) ? src[(size_t)k * 128 + n] : 0.0f;
    a.d[wi][idx] = f2b(v);
}

// ---------------- P precompute (standalone, used once before step 0) ----------------
__global__ __launch_bounds__(256, 2) void pnode_mfma(
    const u16* __restrict__ h,
    const u16* __restrict__ WsF, const u16* __restrict__ WdF,
    u16* __restrict__ Ps, u16* __restrict__ Pd) {
    __shared__ u16 t1[64 * 136];
    const int tid = threadIdx.x;
    const int lane = tid & 63, w = tid >> 6, wr = w >> 1, wc = w & 1;
    const int cl = lane & 15, q8 = (lane >> 4) * 8;
    const int row0 = blockIdx.x * 64;
    const int rbase = wr * 32;

    bf16x8 aA[2][4];
    #pragma unroll
    for (int rt = 0; rt < 2; rt++) {
        const u16* hp = h + (size_t)(row0 + rbase + rt * 16 + cl) * HD + q8;
        #pragma unroll
        for (int k0 = 0; k0 < 4; k0++) aA[rt][k0] = *(const bf16x8*)(hp + k0 * 32);
    }
    bf16x8 wB[16];
    f32x4 acc[2][4];

    load_w16(WsF, wc, lane, wB);
    zero_accs<2>(acc);
    #pragma unroll
    for (int k0 = 0; k0 < 4; k0++) {
        const bf16x8 wf[4] = {wB[k0], wB[4 + k0], wB[8 + k0], wB[12 + k0]};
        #pragma unroll
        for (int rt = 0; rt < 2; rt++) mfma4T(aA[rt][k0], wf, acc[rt]);
    }
    store_T_perm<2>(t1, rbase, wc, lane, acc);
    epi_plain<2>(t1, Ps, row0, rbase, NNDP, wc, lane);

    load_w16(WdF, wc, lane, wB);
    zero_accs<2>(acc);
    #pragma unroll
    for (int k0 = 0; k0 < 4; k0++) {
        const bf16x8 wf[4] = {wB[k0], wB[4 + k0], wB[8 + k0], wB[12 + k0]};
        #pragma unroll
        for (int rt = 0; rt < 2; rt++) mfma4T(aA[rt][k0], wf, acc[rt]);
    }
    store_T_perm<2>(t1, rbase, wc, lane, acc);
    epi_plain<2>(t1, Pd, row0, rbase, NNDP, wc, lane);
}

// ---------------- encoder (BM=64, 4 waves, RT=2): W2/W3 reg-preload ----------------
__global__ __launch_bounds__(256, 3) void enc_mfma(
    const float* __restrict__ in, int Kin, int nrows, const int4* __restrict__ epk,
    const u16* __restrict__ W1f, const float* __restrict__ b1,
    const u16* __restrict__ W2f, const float* __restrict__ b2,
    const u16* __restrict__ W3f, const float* __restrict__ b3,
    u16* __restrict__ out) {
    __shared__ u16 t1[64 * 136];
    __shared__ u16 t2[64 * 136];
    const int tid = threadIdx.x;
    const int lane = tid & 63, w = tid >> 6, wr = w >> 1, wc = w & 1;
    const int cl = lane & 15, q8 = (lane >> 4) * 8;
    const int row0 = blockIdx.x * 64;
    const int rbase = wr * 32;

    bf16x8 wW[16];
    load_w16(W2f, wc, lane, wW);   // in flight during input gather + L1

    f32x4 acc[2][4];
    zero_accs<2>(acc);
    bf16x8 a[2];
    #pragma unroll
    for (int rt = 0; rt < 2; rt++) {
        a[rt] = (bf16x8){0, 0, 0, 0, 0, 0, 0, 0};
        int grow = row0 + rbase + rt * 16 + cl;
        if (q8 == 0 && grow < nrows) {
            int irow = epk ? epk[grow].z : grow;
            const float* xr = in + (size_t)irow * Kin;
            if (Kin == 4) {
                float4 v = *(const float4*)xr;
                a[rt][0] = (short)f2b(v.x); a[rt][1] = (short)f2b(v.y);
                a[rt][2] = (short)f2b(v.z); a[rt][3] = (short)f2b(v.w);
            } else {
                a[rt][0] = (short)f2b(xr[0]); a[rt][1] = (short)f2b(xr[1]);
                a[rt][2] = (short)f2b(xr[2]);
            }
        }
    }
    {
        const u16* b1p = W1f + (size_t)(wc * 4) * 512 + lane * 8;  // KC=1
        bf16x8 wf[4];
        #pragma unroll
        for (int ct = 0; ct < 4; ct++) wf[ct] = *(const bf16x8*)(b1p + ct * 512);
        #pragma unroll
        for (int rt = 0; rt < 2; rt++) mfma4T(a[rt], wf, acc[rt]);
    }
    store_T<2, true>(t1, rbase, wc, lane, acc, b1);
    __syncthreads();
    zero_accs<2>(acc);
    gemm_reg_T<2>(t1, rbase, wW, lane, acc);
    load_w16(W3f, wc, lane, wW);   // W3 in flight across store+bar
    store_T<2, true>(t2, rbase, wc, lane, acc, b2);
    __syncthreads();
    zero_accs<2>(acc);
    gemm_reg_T<2>(t2, rbase, wW, lane, acc);
    store_T<2, false>(t1, rbase, wc, lane, acc, b3);   // t1 reads done pre-bar2
    epi_plain<2>(t1, out, row0, rbase, nrows, wc, lane);
}

// ---------------- edge step (BM=96, 4 waves, RT=3): 3 blocks/CU, XCD swizzle ----------------
__global__ __launch_bounds__(256, 3) void edge_mfma(
    u16* __restrict__ e, const int4* __restrict__ epk,
    const u16* __restrict__ Ps, const u16* __restrict__ Pd,
    const u16* __restrict__ W1eF, const float* __restrict__ b1,
    const u16* __restrict__ W2f, const float* __restrict__ b2,
    const u16* __restrict__ W3f, const float* __restrict__ b3) {
    __shared__ u16 t1[96 * 136];
    __shared__ u16 t2[96 * 136];
    const int tid = threadIdx.x;
    const int lane = tid & 63, w = tid >> 6, wr = w >> 1, wc = w & 1;
    const int cl = lane & 15, q = lane >> 4, q8 = q * 8;
    const int row0 = xcd_swz(blockIdx.x, gridDim.x) * 96;
    const int rbase = wr * 48;

    bf16x8 wA[16], wB[16];
    load_w16(W1eF, wc, lane, wA);  // L1e weights: in flight during epk/P gather
    load_w16(W2f, wc, lane, wB);   // L2 weights: in flight during L1 phase

    int srcv[3], dstv[3];
    const u16* epv[3];
    #pragma unroll
    for (int rt = 0; rt < 3; rt++) {
        int myrow = row0 + rbase + rt * 16 + cl;
        int4 pk = epk[myrow];
        srcv[rt] = pk.x; dstv[rt] = pk.y;
        epv[rt] = e + (size_t)myrow * HD + q8;
    }

    // acc init = Ps[src] + Pd[dst]; permuted P layout -> one 32B contiguous read per P
    const int pofs = wc * 64 + q * 16;
    f32x4 acc[3][4];
    #pragma unroll
    for (int rt = 0; rt < 3; rt++) {
        const u16* ps = Ps + (size_t)srcv[rt] * HD + pofs;
        const u16* pd = Pd + (size_t)dstv[rt] * HD + pofs;
        bf16x8 a0 = *(const bf16x8*)ps;
        bf16x8 a1 = *(const bf16x8*)(ps + 8);
        bf16x8 b0 = *(const bf16x8*)pd;
        bf16x8 b1v = *(const bf16x8*)(pd + 8);
        #pragma unroll
        for (int ct = 0; ct < 2; ct++)
            #pragma unroll
            for (int i = 0; i < 4; i++)
                acc[rt][ct][i] = b2f((u16)a0[ct * 4 + i]) + b2f((u16)b0[ct * 4 + i]);
        #pragma unroll
        for (int ct = 2; ct < 4; ct++)
            #pragma unroll
            for (int i = 0; i < 4; i++)
                acc[rt][ct][i] = b2f((u16)a1[(ct - 2) * 4 + i]) + b2f((u16)b1v[(ct - 2) * 4 + i]);
    }
    // W1e · e section (K=128), register-resident weights
    #pragma unroll
    for (int k0 = 0; k0 < 4; k0++) {
        const bf16x8 wf[4] = {wA[k0], wA[4 + k0], wA[8 + k0], wA[12 + k0]};
        #pragma unroll
        for (int rt = 0; rt < 3; rt++) {
            bf16x8 a = *(const bf16x8*)(epv[rt] + k0 * 32);
            mfma4T(a, wf, acc[rt]);
        }
    }
    store_T<3, true>(t1, rbase, wc, lane, acc, b1);
    __syncthreads();                                   // bar1
    zero_accs<3>(acc);
    gemm_reg_T<3>(t1, rbase, wB, lane, acc);
    load_w16(W3f, wc, lane, wB);                       // W3 in flight across store+bar2
    store_T<3, true>(t2, rbase, wc, lane, acc, b2);
    __syncthreads();                                   // bar2
    // prefetch epilogue e_old now -> latency hides under the L3 gemm + store
    bf16x8 eold[6];
    #pragma unroll
    for (int p = 0; p < 6; p++) {
        const int lrow = rbase + p * 8 + (lane >> 3);
        const int col = wc * 64 + (lane & 7) * 8;
        eold[p] = *(const bf16x8*)(e + (size_t)(row0 + lrow) * HD + col);
    }
    zero_accs<3>(acc);
    gemm_reg_T<3>(t2, rbase, wB, lane, acc);
    store_T<3, false>(t1, rbase, wc, lane, acc, b3);   // t1 reads done pre-bar2
    // wave-private coalesced epilogue with prefetched residual
    #pragma unroll
    for (int p = 0; p < 6; p++) {
        const int lrow = rbase + p * 8 + (lane >> 3);
        const int col = wc * 64 + (lane & 7) * 8;
        bf16x8 tv = *(const bf16x8*)(t1 + lrow * 136 + col);
        bf16x8 res;
        #pragma unroll
        for (int k = 0; k < 8; k++)
            res[k] = (short)f2b(b2f((u16)tv[k]) + b2f((u16)eold[p][k]));
        *(bf16x8*)(e + (size_t)(row0 + lrow) * HD + col) = res;
    }
}

// ---------------- node step (BM=64, 4 waves, RT=2): W2/W3 reg-preload + fused P ----------------
__global__ __launch_bounds__(256, 3) void node_mfma(
    u16* __restrict__ h, const u16* __restrict__ e, const int* __restrict__ offsets,
    const u16* __restrict__ W1f, const float* __restrict__ b1,
    const u16* __restrict__ W2f, const float* __restrict__ b2,
    const u16* __restrict__ W3f, const float* __restrict__ b3,
    const u16* __restrict__ W1sNx, const u16* __restrict__ W1dNx,
    u16* __restrict__ Ps, u16* __restrict__ Pd) {
    __shared__ u16 tb[64 * 136];
    __shared__ u16 aggT[64 * 136];
    const int tid = threadIdx.x;
    const int lane = tid & 63, w = tid >> 6, wr = w >> 1, wc = w & 1;
    const int cl = lane & 15, q8 = (lane >> 4) * 8;
    const int row0 = xcd_swz(blockIdx.x, gridDim.x) * 64;
    const int rbase = wr * 32;

    bf16x8 wW[16];
    load_w16(W2f, wc, lane, wW);   // W2 in flight during the whole aggregation phase

    {   // aggregation: 4 thr/row x 32 ch; j-unrolled for ILP
        const int r = tid >> 2, sgi = tid & 3;
        const int node = row0 + r;
        const int beg = offsets[node], end = offsets[node + 1];
        float s[32];
        #pragma unroll
        for (int k = 0; k < 32; k++) s[k] = 0.0f;
        const u16* ebase = e + sgi * 32;
        int j = beg;
        for (; j + 2 <= end; j += 2) {
            const bf16x8* e0 = (const bf16x8*)(ebase + (size_t)j * HD);
            const bf16x8* e1 = (const bf16x8*)(ebase + (size_t)(j + 1) * HD);
            bf16x8 v0 = e0[0], v1 = e0[1], v2 = e0[2], v3 = e0[3];
            bf16x8 u0 = e1[0], u1 = e1[1], u2 = e1[2], u3 = e1[3];
            #pragma unroll
            for (int k = 0; k < 8; k++) {
                s[k]      += b2f((u16)v0[k]) + b2f((u16)u0[k]);
                s[8 + k]  += b2f((u16)v1[k]) + b2f((u16)u1[k]);
                s[16 + k] += b2f((u16)v2[k]) + b2f((u16)u2[k]);
                s[24 + k] += b2f((u16)v3[k]) + b2f((u16)u3[k]);
            }
        }
        if (j < end) {
            const bf16x8* e0 = (const bf16x8*)(ebase + (size_t)j * HD);
            bf16x8 v0 = e0[0], v1 = e0[1], v2 = e0[2], v3 = e0[3];
            #pragma unroll
            for (int k = 0; k < 8; k++) {
                s[k]      += b2f((u16)v0[k]);
                s[8 + k]  += b2f((u16)v1[k]);
                s[16 + k] += b2f((u16)v2[k]);
                s[24 + k] += b2f((u16)v3[k]);
            }
        }
        #pragma unroll
        for (int q = 0; q < 4; q++) {
            bf16x8 o;
            #pragma unroll
            for (int k = 0; k < 8; k++) o[k] = (short)f2b(s[q * 8 + k]);
            *(bf16x8*)(aggT + r * 136 + sgi * 32 + q * 8) = o;
        }
    }
    __syncthreads();                                   // bar1: aggT visible

    f32x4 acc[2][4];
    zero_accs<2>(acc);
    const u16* b1p = W1f + (size_t)(wc * 32) * 512 + lane * 8;  // KC1=8
    const u16* hp[2];
    #pragma unroll
    for (int rt = 0; rt < 2; rt++)
        hp[rt] = h + (size_t)(row0 + rbase + rt * 16 + cl) * HD + q8;
    #pragma unroll
    for (int k0 = 0; k0 < 4; k0++) {   // h section (global)
        bf16x8 wf[4];
        #pragma unroll
        for (int ct = 0; ct < 4; ct++) wf[ct] = *(const bf16x8*)(b1p + (ct * 8 + k0) * 512);
        #pragma unroll
        for (int rt = 0; rt < 2; rt++) {
            bf16x8 a = *(const bf16x8*)(hp[rt] + k0 * 32);
            mfma4T(a, wf, acc[rt]);
        }
    }
    #pragma unroll
    for (int k0 = 0; k0 < 4; k0++) {   // agg section (LDS)
        bf16x8 wf[4];
        #pragma unroll
        for (int ct = 0; ct < 4; ct++) wf[ct] = *(const bf16x8*)(b1p + (ct * 8 + 4 + k0) * 512);
        #pragma unroll
        for (int rt = 0; rt < 2; rt++) {
            bf16x8 a = *(const bf16x8*)(aggT + (rbase + rt * 16 + cl) * 136 + k0 * 32 + q8);
            mfma4T(a, wf, acc[rt]);
        }
    }
    store_T<2, true>(tb, rbase, wc, lane, acc, b1);
    __syncthreads();                                   // bar2
    zero_accs<2>(acc);
    gemm_reg_T<2>(tb, rbase, wW, lane, acc);           // W2 from registers
    load_w16(W3f, wc, lane, wW);                       // W3 in flight across store+bar3
    store_T<2, true>(aggT, rbase, wc, lane, acc, b2);  // aggT safe after bar2
    __syncthreads();                                   // bar3
    // prefetch epilogue h_old -> latency hides under the L3 gemm + store
    bf16x8 hold[4];
    #pragma unroll
    for (int p = 0; p < 4; p++) {
        const int lrow = rbase + p * 8 + (lane >> 3);
        const int col = wc * 64 + (lane & 7) * 8;
        hold[p] = *(const bf16x8*)(h + (size_t)(row0 + lrow) * HD + col);
    }
    zero_accs<2>(acc);
    gemm_reg_T<2>(aggT, rbase, wW, lane, acc);         // W3 from registers
    store_T<2, false>(tb, rbase, wc, lane, acc, b3);   // tb safe after bar3
    // epilogue: residual, write h_new to global AND back into tb (same wave region)
    #pragma unroll
    for (int p = 0; p < 4; p++) {
        const int lrow = rbase + p * 8 + (lane >> 3);
        const int col = wc * 64 + (lane & 7) * 8;
        bf16x8 tv = *(const bf16x8*)(tb + lrow * 136 + col);
        bf16x8 res;
        #pragma unroll
        for (int k = 0; k < 8; k++)
            res[k] = (short)f2b(b2f((u16)tv[k]) + b2f((u16)hold[p][k]));
        *(bf16x8*)(h + (size_t)(row0 + lrow) * HD + col) = res;
        *(bf16x8*)(tb + lrow * 136 + col) = res;
    }
    if (W1sNx) {   // fused P precompute for the NEXT step (tb now holds h_new)
        __syncthreads();                               // bar4: tb h_new + aggT free
        load_w16(W1sNx, wc, lane, wW);
        f32x4 pac[2][4];
        zero_accs<2>(pac);
        gemm_reg_T<2>(tb, rbase, wW, lane, pac);
        store_T_perm<2>(aggT, rbase, wc, lane, pac);
        epi_plain<2>(aggT, Ps, row0, rbase, NNDP, wc, lane);
        load_w16(W1dNx, wc, lane, wW);
        zero_accs<2>(pac);
        gemm_reg_T<2>(tb, rbase, wW, lane, pac);
        store_T_perm<2>(aggT, rbase, wc, lane, pac);
        epi_plain<2>(aggT, Pd, row0, rbase, NNDP, wc, lane);
    }
}

// ---------------- decoder: h -> MLP(H,H,OUT=2) fp32 out ----------------
__global__ __launch_bounds__(256, 4) void dec_mfma(
    const u16* __restrict__ h,
    const u16* __restrict__ W1f, const float* __restrict__ b1,
    const u16* __restrict__ W2f, const float* __restrict__ b2,
    const float* __restrict__ W3, const float* __restrict__ b3,
    float* __restrict__ out) {
    __shared__ u16 t1[32 * 136];
    __shared__ u16 t2[32 * 136];
    const int tid = threadIdx.x;
    const int lane = tid & 63, w = tid >> 6, wr = w >> 1, wc = w & 1;
    const int cl = lane & 15, q8 = (lane >> 4) * 8;
    const int row0 = blockIdx.x * 32;
    const int rbase = wr * 16;
    const u16* hp = h + (size_t)(row0 + rbase + cl) * HD + q8;

    f32x4 acc[1][4];
    zero_accs<1>(acc);
    const u16* b1p = W1f + (size_t)(wc * 16) * 512 + lane * 8;  // KC=4
    #pragma unroll
    for (int k0 = 0; k0 < 4; k0++) {
        bf16x8 wf[4];
        #pragma unroll
        for (int ct = 0; ct < 4; ct++) wf[ct] = *(const bf16x8*)(b1p + (ct * 4 + k0) * 512);
        bf16x8 a = *(const bf16x8*)(hp + k0 * 32);
        mfma4T(a, wf, acc[0]);
    }
    store_T<1, true>(t1, rbase, wc, lane, acc, b1);
    __syncthreads();
    zero_accs<1>(acc);
    gemm_lds_T<4, 1>(t1, rbase, W2f, wc, lane, acc);
    store_T<1, true>(t2, rbase, wc, lane, acc, b2);
    __syncthreads();
    if (tid < 64) {
        const int rr = tid >> 1, o = tid & 1;
        const int grow = row0 + rr;
        if (grow < NND) {
            float a = b3[o];
            for (int k = 0; k < HD; k++) a += b2f(t2[rr * 136 + k]) * W3[k * 2 + o];
            out[(size_t)grow * 2 + o] = a;
        }
    }
}

extern "C" void kernel_launch(void* const* d_in, const int* in_sizes, int n_in,
                              void* d_out, int out_size, void* d_ws, size_t ws_size,
                              hipStream_t stream) {
    (void)in_sizes; (void)n_in; (void)out_size; (void)ws_size;
    const float* x    = (const float*)d_in[0];
    const float* eatt = (const float*)d_in[1];
    const int*   eidx = (const int*)d_in[2];
    const float *neW1 = (const float*)d_in[3],  *neb1 = (const float*)d_in[4];
    const float *neW2 = (const float*)d_in[5],  *neb2 = (const float*)d_in[6];
    const float *neW3 = (const float*)d_in[7],  *neb3 = (const float*)d_in[8];
    const float *eeW1 = (const float*)d_in[9],  *eeb1 = (const float*)d_in[10];
    const float *eeW2 = (const float*)d_in[11], *eeb2 = (const float*)d_in[12];
    const float *eeW3 = (const float*)d_in[13], *eeb3 = (const float*)d_in[14];
    const float *peW1 = (const float*)d_in[15], *peb1 = (const float*)d_in[16];
    const float *peW2 = (const float*)d_in[17], *peb2 = (const float*)d_in[18];
    const float *peW3 = (const float*)d_in[19], *peb3 = (const float*)d_in[20];
    const float *pnW1 = (const float*)d_in[21], *pnb1 = (const float*)d_in[22];
    const float *pnW2 = (const float*)d_in[23], *pnb2 = (const float*)d_in[24];
    const float *pnW3 = (const float*)d_in[25], *pnb3 = (const float*)d_in[26];
    const float *ndW1 = (const float*)d_in[27], *ndb1 = (const float*)d_in[28];
    const float *ndW2 = (const float*)d_in[29], *ndb2 = (const float*)d_in[30];
    const float *ndW3 = (const float*)d_in[31], *ndb3 = (const float*)d_in[32];

    char* ws = (char*)d_ws;
    u16*   h       = (u16*)ws;                      // [NNDP][HD] bf16
    u16*   e       = (u16*)(ws + 12812288);         // [NEDP][HD] bf16 (dst-sorted)
    int*   bsum    = (int*)(ws + 115245056);
    int*   bbase   = (int*)(ws + 115246080);
    int*   counts  = (int*)(ws + 115247104);
    int*   cursors = (int*)(ws + 115447296);
    int*   offsets = (int*)(ws + 115647488);        // [NNDP+1]
    int4*  epk     = (int4*)(ws + 115847696);       // [NEDP] {src,dst,perm,0}
    u16*   Ps      = (u16*)(ws + 122249744);        // [NNDP][HD] bf16 (permuted cols)
    u16*   Pd      = (u16*)(ws + 135062032);        // [NNDP][HD] bf16 (permuted cols)
    u16*   wts     = (u16*)(ws + 147874320);

    u16* p = wts;
    u16 *neW1t = p; p += 128 * 32;
    u16 *neW2t = p; p += 128 * 128;
    u16 *neW3t = p; p += 128 * 128;
    u16 *eeW1t = p; p += 128 * 32;
    u16 *eeW2t = p; p += 128 * 128;
    u16 *eeW3t = p; p += 128 * 128;
    u16 *peW1sF[NSTEP], *peW1dF[NSTEP], *peW1eF[NSTEP], *peW2t[NSTEP], *peW3t[NSTEP];
    u16 *pnW1t[NSTEP], *pnW2t[NSTEP], *pnW3t[NSTEP];
    for (int t = 0; t < NSTEP; t++) {
        peW1sF[t] = p; p += 128 * 128;
        peW1dF[t] = p; p += 128 * 128;
        peW1eF[t] = p; p += 128 * 128;
        peW2t[t]  = p; p += 128 * 128;
        peW3t[t]  = p; p += 128 * 128;
    }
    for (int t = 0; t < NSTEP; t++) {
        pnW1t[t] = p; p += 128 * 256;
        pnW2t[t] = p; p += 128 * 128;
        pnW3t[t] = p; p += 128 * 128;
    }
    u16 *ndW1t = p; p += 128 * 128;
    u16 *ndW2t = p; p += 128 * 128;

    hipMemsetAsync(counts, 0, NNDP * sizeof(int), stream);
    hipMemsetAsync(epk + NED, 0, (NEDP - NED) * sizeof(int4), stream);
    count_kernel<<<(NED + 255) / 256, 256, 0, stream>>>(eidx, counts);
    bsum_kernel<<<NSB, 256, 0, stream>>>(counts, bsum);
    bscan_kernel<<<1, 256, 0, stream>>>(bsum, bbase, offsets);
    blocal_kernel<<<NSB, 256, 0, stream>>>(counts, bbase, offsets, cursors);
    fill_kernel<<<(NED + 255) / 256, 256, 0, stream>>>(eidx, cursors, epk);

    WPall wa;
    int wn = 0;
    auto ADD = [&](const float* s, u16* d, int K, int Kp) {
        wa.s[wn] = s; wa.d[wn] = d; wa.K[wn] = K; wa.Kp[wn] = Kp; wn++;
    };
    ADD(neW1, neW1t, 4, 32);
    ADD(neW2, neW2t, 128, 128);
    ADD(neW3, neW3t, 128, 128);
    ADD(eeW1, eeW1t, 3, 32);
    ADD(eeW2, eeW2t, 128, 128);
    ADD(eeW3, eeW3t, 128, 128);
    for (int t = 0; t < NSTEP; t++) {
        const float* base = peW1 + (size_t)t * 384 * 128;
        ADD(base,             peW1sF[t], 128, 128);   // rows 0..127   (h[src])
        ADD(base + 128 * 128, peW1dF[t], 128, 128);   // rows 128..255 (h[dst])
        ADD(base + 256 * 128, peW1eF[t], 128, 128);   // rows 256..383 (e)
        ADD(peW2 + (size_t)t * 128 * 128, peW2t[t], 128, 128);
        ADD(peW3 + (size_t)t * 128 * 128, peW3t[t], 128, 128);
        ADD(pnW1 + (size_t)t * 256 * 128, pnW1t[t], 256, 256);
        ADD(pnW2 + (size_t)t * 128 * 128, pnW2t[t], 128, 128);
        ADD(pnW3 + (size_t)t * 128 * 128, pnW3t[t], 128, 128);
    }
    ADD(ndW1, ndW1t, 128, 128);
    ADD(ndW2, ndW2t, 128, 128);
    wprep_all<<<dim3(128, NWP), 256, 0, stream>>>(wa);

    enc_mfma<<<NNDP / 64, 256, 0, stream>>>(x, 4, NND, nullptr,
                                            neW1t, neb1, neW2t, neb2, neW3t, neb3, h);
    enc_mfma<<<NED / 64, 256, 0, stream>>>(eatt, 3, NED, epk,
                                           eeW1t, eeb1, eeW2t, eeb2, eeW3t, eeb3, e);
    pnode_mfma<<<NNDP / 64, 256, 0, stream>>>(h, peW1sF[0], peW1dF[0], Ps, Pd);

    for (int t = 0; t < NSTEP; t++) {
        edge_mfma<<<NEDP / 96, 256, 0, stream>>>(
            e, epk, Ps, Pd,
            peW1eF[t], peb1 + (size_t)t * HD,
            peW2t[t],  peb2 + (size_t)t * HD,
            peW3t[t],  peb3 + (size_t)t * HD);
        const bool last = (t + 1 == NSTEP);
        node_mfma<<<NNDP / 64, 256, 0, stream>>>(
            h, e, offsets,
            pnW1t[t], pnb1 + (size_t)t * HD,
            pnW2t[t], pnb2 + (size_t)t * HD,
            pnW3t[t], pnb3 + (size_t)t * HD,
            last ? nullptr : peW1sF[t + 1],
            last ? nullptr : peW1dF[t + 1],
            Ps, Pd);
    }
    dec_mfma<<<NNDP / 32, 256, 0, stream>>>(h, ndW1t, ndb1, ndW2t, ndb2, ndW3, ndb3, (float*)d_out);
}

// Round 20
// 529.793 us; speedup vs baseline: 1.0393x; 1.0393x over previous
//
#include <hip/hip_runtime.h>
#include <hip/hip_bf16.h>
#include <cstddef>

#define NND 50000
#define NNDP 50048    // padded: multiple of 64
#define NED 400000    // divisible by 128
#define HD 128
#define NSTEP 3
#define NSB 196       // scan blocks: 196*256 >= NNDP
#define NWP 32

using u16 = unsigned short;
typedef __attribute__((ext_vector_type(8))) short bf16x8;
typedef __attribute__((ext_vector_type(4))) float f32x4;

__device__ __forceinline__ u16 f2b(float f) {
    __hip_bfloat16 b = __float2bfloat16(f);
    union { __hip_bfloat16 b; u16 u; } v; v.b = b;
    return v.u;
}
__device__ __forceinline__ float b2f(u16 u) {
    union { unsigned u; float f; } v; v.u = ((unsigned)u) << 16;
    return v.f;
}

template <int RT>
__device__ __forceinline__ void zero_accs(f32x4 (&acc)[RT][4]) {
    #pragma unroll
    for (int g = 0; g < RT; g++)
        #pragma unroll
        for (int i = 0; i < 4; i++) acc[g][i] = (f32x4)(0.0f);
}

// Transposed-C: D = mfma(A=W_frag, B=act_frag); C/D: lane&15 <-> data-row,
// (lane>>4)*4+i <-> out-CHANNEL (4 consecutive channels per lane per ct).
__device__ __forceinline__ void mfma4T(bf16x8 act, const bf16x8 (&wf)[4], f32x4 (&accr)[4]) {
    accr[0] = __builtin_amdgcn_mfma_f32_16x16x32_bf16(wf[0], act, accr[0], 0, 0, 0);
    accr[1] = __builtin_amdgcn_mfma_f32_16x16x32_bf16(wf[1], act, accr[1], 0, 0, 0);
    accr[2] = __builtin_amdgcn_mfma_f32_16x16x32_bf16(wf[2], act, accr[2], 0, 0, 0);
    accr[3] = __builtin_amdgcn_mfma_f32_16x16x32_bf16(wf[3], act, accr[3], 0, 0, 0);
}

// Preload a K=128 layer's 16 weight fragments into registers.
__device__ __forceinline__ void load_w16(const u16* __restrict__ Wf, int wc, int lane,
                                         bf16x8 (&wB)[16]) {
    const u16* bp = Wf + (size_t)(wc * 16) * 512 + lane * 8;
    #pragma unroll
    for (int i = 0; i < 16; i++) wB[i] = *(const bf16x8*)(bp + i * 512);
}

// K=128 layer with REGISTER-resident weights; act rows from LDS t (stride 136).
template <int RT>
__device__ __forceinline__ void gemm_reg_T(const u16* t, int rbase, const bf16x8 (&wB)[16],
                                           int lane, f32x4 (&acc)[RT][4]) {
    const int cl = lane & 15, q8 = (lane >> 4) * 8;
    #pragma unroll
    for (int k0 = 0; k0 < 4; k0++) {
        const bf16x8 wf[4] = {wB[k0], wB[4 + k0], wB[8 + k0], wB[12 + k0]};
        #pragma unroll
        for (int rt = 0; rt < RT; rt++) {
            bf16x8 a = *(const bf16x8*)(t + (rbase + rt * 16 + cl) * 136 + k0 * 32 + q8);
            mfma4T(a, wf, acc[rt]);
        }
    }
}

// K = KC*32 layer, act rows from LDS t (stride 136), weights fragment-major (global).
template <int KC, int RT>
__device__ __forceinline__ void gemm_lds_T(const u16* t, int rbase,
                                           const u16* __restrict__ Wf,
                                           int wc, int lane, f32x4 (&acc)[RT][4]) {
    const int cl = lane & 15, q8 = (lane >> 4) * 8;
    const u16* bp = Wf + (size_t)(wc * 4 * KC) * 512 + lane * 8;
    #pragma unroll
    for (int k0 = 0; k0 < KC; k0++) {
        bf16x8 wf[4];
        #pragma unroll
        for (int ct = 0; ct < 4; ct++) wf[ct] = *(const bf16x8*)(bp + (ct * KC + k0) * 512);
        #pragma unroll
        for (int rt = 0; rt < RT; rt++) {
            bf16x8 a = *(const bf16x8*)(t + (rbase + rt * 16 + cl) * 136 + k0 * 32 + q8);
            mfma4T(a, wf, acc[rt]);
        }
    }
}

// Store transposed-C tile to LDS: one ds_write_b64 per (rt,ct).
template <int RT, bool RELU>
__device__ __forceinline__ void store_T(u16* T, int rbase, int wc, int lane,
        const f32x4 (&acc)[RT][4], const float* __restrict__ bias) {
    const int cl = lane & 15, q = lane >> 4;
    float4 bv[4];
    #pragma unroll
    for (int ct = 0; ct < 4; ct++)
        bv[ct] = *(const float4*)(bias + wc * 64 + ct * 16 + q * 4);
    #pragma unroll
    for (int rt = 0; rt < RT; rt++) {
        const int row = rbase + rt * 16 + cl;
        #pragma unroll
        for (int ct = 0; ct < 4; ct++) {
            float v0 = acc[rt][ct][0] + bv[ct].x;
            float v1 = acc[rt][ct][1] + bv[ct].y;
            float v2 = acc[rt][ct][2] + bv[ct].z;
            float v3 = acc[rt][ct][3] + bv[ct].w;
            if (RELU) {
                v0 = fmaxf(v0, 0.f); v1 = fmaxf(v1, 0.f);
                v2 = fmaxf(v2, 0.f); v3 = fmaxf(v3, 0.f);
            }
            uint2 pk;
            pk.x = (unsigned)f2b(v0) | ((unsigned)f2b(v1) << 16);
            pk.y = (unsigned)f2b(v2) | ((unsigned)f2b(v3) << 16);
            *(uint2*)(T + row * 136 + wc * 64 + ct * 16 + q * 4) = pk;
        }
    }
}

// store_T without bias/relu, PERMUTED column: colp = wc*64 + q*16 + ct*4.
template <int RT>
__device__ __forceinline__ void store_T_perm(u16* T, int rbase, int wc, int lane,
        const f32x4 (&acc)[RT][4]) {
    const int cl = lane & 15, q = lane >> 4;
    #pragma unroll
    for (int rt = 0; rt < RT; rt++) {
        const int row = rbase + rt * 16 + cl;
        #pragma unroll
        for (int ct = 0; ct < 4; ct++) {
            uint2 pk;
            pk.x = (unsigned)f2b(acc[rt][ct][0]) | ((unsigned)f2b(acc[rt][ct][1]) << 16);
            pk.y = (unsigned)f2b(acc[rt][ct][2]) | ((unsigned)f2b(acc[rt][ct][3]) << 16);
            *(uint2*)(T + row * 136 + wc * 64 + q * 16 + ct * 4) = pk;
        }
    }
}

// Coalesced wave-private epilogue: plain copy.
template <int RT>
__device__ __forceinline__ void epi_plain(const u16* T, u16* __restrict__ base, int row0,
        int rbase, int nrows, int wc, int lane) {
    #pragma unroll
    for (int p = 0; p < RT * 2; p++) {
        const int lrow = rbase + p * 8 + (lane >> 3);
        const int col = wc * 64 + (lane & 7) * 8;
        const int grow = row0 + lrow;
        if (grow < nrows) {
            bf16x8 tv = *(const bf16x8*)(T + lrow * 136 + col);
            *(bf16x8*)(base + (size_t)grow * HD + col) = tv;
        }
    }
}

// ---------------- CSR build (hierarchical scan, all parallel) ----------------
__global__ void count_kernel(const int* __restrict__ eidx, int* __restrict__ counts) {
    int i = blockIdx.x * 256 + threadIdx.x;
    if (i < NED) atomicAdd(&counts[eidx[NED + i]], 1);
}

__global__ __launch_bounds__(256) void bsum_kernel(const int* __restrict__ counts,
                                                   int* __restrict__ bsum) {
    __shared__ int sm[256];
    const int i = threadIdx.x, b = blockIdx.x;
    const int idx = b * 256 + i;
    sm[i] = (idx < NNDP) ? counts[idx] : 0;
    __syncthreads();
    for (int ofs = 128; ofs > 0; ofs >>= 1) {
        if (i < ofs) sm[i] += sm[i + ofs];
        __syncthreads();
    }
    if (i == 0) bsum[b] = sm[0];
}

__global__ __launch_bounds__(256) void bscan_kernel(const int* __restrict__ bsum,
                                                    int* __restrict__ bbase,
                                                    int* __restrict__ offsets) {
    __shared__ int sm[256];
    const int i = threadIdx.x;
    int v = (i < NSB) ? bsum[i] : 0;
    sm[i] = v;
    __syncthreads();
    for (int ofs = 1; ofs < 256; ofs <<= 1) {
        int t = (i >= ofs) ? sm[i - ofs] : 0;
        __syncthreads();
        sm[i] += t;
        __syncthreads();
    }
    if (i < NSB) bbase[i] = sm[i] - v;
    if (i == NSB - 1) offsets[NNDP] = sm[i];
}

__global__ __launch_bounds__(256) void blocal_kernel(const int* __restrict__ counts,
                                                     const int* __restrict__ bbase,
                                                     int* __restrict__ offsets,
                                                     int* __restrict__ cursors) {
    __shared__ int sm[256];
    const int i = threadIdx.x, b = blockIdx.x;
    const int idx = b * 256 + i;
    int v = (idx < NNDP) ? counts[idx] : 0;
    sm[i] = v;
    __syncthreads();
    for (int ofs = 1; ofs < 256; ofs <<= 1) {
        int t = (i >= ofs) ? sm[i - ofs] : 0;
        __syncthreads();
        sm[i] += t;
        __syncthreads();
    }
    if (idx < NNDP) {
        int excl = sm[i] - v + bbase[b];
        offsets[idx] = excl;
        cursors[idx] = excl;
    }
}

__global__ void fill_kernel(const int* __restrict__ eidx, int* __restrict__ cursors,
                            int4* __restrict__ epk) {
    int i = blockIdx.x * 256 + threadIdx.x;
    if (i >= NED) return;
    int d = eidx[NED + i];
    int pos = atomicAdd(&cursors[d], 1);
    int4 v; v.x = eidx[i]; v.y = d; v.z = i; v.w = 0;
    epk[pos] = v;
}

// ---------------- fused weight prep ----------------
struct WPall {
    const float* s[NWP];
    u16* d[NWP];
    int K[NWP];
    int Kp[NWP];
};

__global__ void wprep_all(WPall a) {
    const int wi = blockIdx.y;
    const int Kp = a.Kp[wi];
    int idx = blockIdx.x * 256 + threadIdx.x;
    if (idx >= 128 * Kp) return;
    const int K = a.K[wi];
    const float* __restrict__ src = a.s[wi];
    int j = idx & 7, lane = (idx >> 3) & 63, rest = idx >> 9;
    int KC = Kp >> 5;
    int k0 = rest % KC, n0 = rest / KC;
    int n = n0 * 16 + (lane & 15);
    int k = k0 * 32 + (lane >> 4) * 8 + j;
    float v = (k < K) ? src[(size_t)k * 128 + n] : 0.0f;
    a.d[wi][idx] = f2b(v);
}

// ---------------- P precompute (standalone, used once before step 0) ----------------
__global__ __launch_bounds__(256, 2) void pnode_mfma(
    const u16* __restrict__ h,
    const u16* __restrict__ WsF, const u16* __restrict__ WdF,
    u16* __restrict__ Ps, u16* __restrict__ Pd) {
    __shared__ u16 t1[64 * 136];
    const int tid = threadIdx.x;
    const int lane = tid & 63, w = tid >> 6, wr = w >> 1, wc = w & 1;
    const int cl = lane & 15, q8 = (lane >> 4) * 8;
    const int row0 = blockIdx.x * 64;
    const int rbase = wr * 32;

    bf16x8 aA[2][4];
    #pragma unroll
    for (int rt = 0; rt < 2; rt++) {
        const u16* hp = h + (size_t)(row0 + rbase + rt * 16 + cl) * HD + q8;
        #pragma unroll
        for (int k0 = 0; k0 < 4; k0++) aA[rt][k0] = *(const bf16x8*)(hp + k0 * 32);
    }
    bf16x8 wB[16];
    f32x4 acc[2][4];

    load_w16(WsF, wc, lane, wB);
    zero_accs<2>(acc);
    #pragma unroll
    for (int k0 = 0; k0 < 4; k0++) {
        const bf16x8 wf[4] = {wB[k0], wB[4 + k0], wB[8 + k0], wB[12 + k0]};
        #pragma unroll
        for (int rt = 0; rt < 2; rt++) mfma4T(aA[rt][k0], wf, acc[rt]);
    }
    store_T_perm<2>(t1, rbase, wc, lane, acc);
    epi_plain<2>(t1, Ps, row0, rbase, NNDP, wc, lane);

    load_w16(WdF, wc, lane, wB);
    zero_accs<2>(acc);
    #pragma unroll
    for (int k0 = 0; k0 < 4; k0++) {
        const bf16x8 wf[4] = {wB[k0], wB[4 + k0], wB[8 + k0], wB[12 + k0]};
        #pragma unroll
        for (int rt = 0; rt < 2; rt++) mfma4T(aA[rt][k0], wf, acc[rt]);
    }
    store_T_perm<2>(t1, rbase, wc, lane, acc);
    epi_plain<2>(t1, Pd, row0, rbase, NNDP, wc, lane);
}

// ---------------- encoder (BM=64, 4 waves, RT=2): 2 barriers ----------------
__global__ __launch_bounds__(256, 4) void enc_mfma(
    const float* __restrict__ in, int Kin, int nrows, const int4* __restrict__ epk,
    const u16* __restrict__ W1f, const float* __restrict__ b1,
    const u16* __restrict__ W2f, const float* __restrict__ b2,
    const u16* __restrict__ W3f, const float* __restrict__ b3,
    u16* __restrict__ out) {
    __shared__ u16 t1[64 * 136];
    __shared__ u16 t2[64 * 136];
    const int tid = threadIdx.x;
    const int lane = tid & 63, w = tid >> 6, wr = w >> 1, wc = w & 1;
    const int cl = lane & 15, q8 = (lane >> 4) * 8;
    const int row0 = blockIdx.x * 64;
    const int rbase = wr * 32;

    f32x4 acc[2][4];
    zero_accs<2>(acc);
    bf16x8 a[2];
    #pragma unroll
    for (int rt = 0; rt < 2; rt++) {
        a[rt] = (bf16x8){0, 0, 0, 0, 0, 0, 0, 0};
        int grow = row0 + rbase + rt * 16 + cl;
        if (q8 == 0 && grow < nrows) {
            int irow = epk ? epk[grow].z : grow;
            const float* xr = in + (size_t)irow * Kin;
            if (Kin == 4) {
                float4 v = *(const float4*)xr;
                a[rt][0] = (short)f2b(v.x); a[rt][1] = (short)f2b(v.y);
                a[rt][2] = (short)f2b(v.z); a[rt][3] = (short)f2b(v.w);
            } else {
                a[rt][0] = (short)f2b(xr[0]); a[rt][1] = (short)f2b(xr[1]);
                a[rt][2] = (short)f2b(xr[2]);
            }
        }
    }
    {
        const u16* b1p = W1f + (size_t)(wc * 4) * 512 + lane * 8;  // KC=1
        bf16x8 wf[4];
        #pragma unroll
        for (int ct = 0; ct < 4; ct++) wf[ct] = *(const bf16x8*)(b1p + ct * 512);
        #pragma unroll
        for (int rt = 0; rt < 2; rt++) mfma4T(a[rt], wf, acc[rt]);
    }
    store_T<2, true>(t1, rbase, wc, lane, acc, b1);
    __syncthreads();
    zero_accs<2>(acc);
    gemm_lds_T<4, 2>(t1, rbase, W2f, wc, lane, acc);
    store_T<2, true>(t2, rbase, wc, lane, acc, b2);
    __syncthreads();
    zero_accs<2>(acc);
    gemm_lds_T<4, 2>(t2, rbase, W3f, wc, lane, acc);
    store_T<2, false>(t1, rbase, wc, lane, acc, b3);   // t1 reads done pre-bar2
    epi_plain<2>(t1, out, row0, rbase, nrows, wc, lane);
}

// ---------------- edge step (BM=128, 4 waves, RT=4): W1e/W2/W3 reg-preload,
//                  dual buffer, 2 barriers, e_old prefetch ----------------
__global__ __launch_bounds__(256, 2) void edge_mfma(
    u16* __restrict__ e, const int4* __restrict__ epk,
    const u16* __restrict__ Ps, const u16* __restrict__ Pd,
    const u16* __restrict__ W1eF, const float* __restrict__ b1,
    const u16* __restrict__ W2f, const float* __restrict__ b2,
    const u16* __restrict__ W3f, const float* __restrict__ b3) {
    __shared__ u16 t1[128 * 136];
    __shared__ u16 t2[128 * 136];
    const int tid = threadIdx.x;
    const int lane = tid & 63, w = tid >> 6, wr = w >> 1, wc = w & 1;
    const int cl = lane & 15, q = lane >> 4, q8 = q * 8;
    const int row0 = blockIdx.x * 128;
    const int rbase = wr * 64;

    bf16x8 wA[16], wB[16];
    load_w16(W1eF, wc, lane, wA);  // L1e weights: in flight during epk/P gather
    load_w16(W2f, wc, lane, wB);   // L2 weights: in flight during whole L1 phase

    int srcv[4], dstv[4];
    const u16* epv[4];
    #pragma unroll
    for (int rt = 0; rt < 4; rt++) {
        int myrow = row0 + rbase + rt * 16 + cl;
        int4 pk = epk[myrow];
        srcv[rt] = pk.x; dstv[rt] = pk.y;
        epv[rt] = e + (size_t)myrow * HD + q8;
    }

    // acc init = Ps[src] + Pd[dst]; permuted P layout -> one 32B contiguous read per P
    const int pofs = wc * 64 + q * 16;
    f32x4 acc[4][4];
    #pragma unroll
    for (int rt = 0; rt < 4; rt++) {
        const u16* ps = Ps + (size_t)srcv[rt] * HD + pofs;
        const u16* pd = Pd + (size_t)dstv[rt] * HD + pofs;
        bf16x8 a0 = *(const bf16x8*)ps;
        bf16x8 a1 = *(const bf16x8*)(ps + 8);
        bf16x8 b0 = *(const bf16x8*)pd;
        bf16x8 b1v = *(const bf16x8*)(pd + 8);
        #pragma unroll
        for (int ct = 0; ct < 2; ct++)
            #pragma unroll
            for (int i = 0; i < 4; i++)
                acc[rt][ct][i] = b2f((u16)a0[ct * 4 + i]) + b2f((u16)b0[ct * 4 + i]);
        #pragma unroll
        for (int ct = 2; ct < 4; ct++)
            #pragma unroll
            for (int i = 0; i < 4; i++)
                acc[rt][ct][i] = b2f((u16)a1[(ct - 2) * 4 + i]) + b2f((u16)b1v[(ct - 2) * 4 + i]);
    }
    // W1e · e section (K=128), register-resident weights
    #pragma unroll
    for (int k0 = 0; k0 < 4; k0++) {
        const bf16x8 wf[4] = {wA[k0], wA[4 + k0], wA[8 + k0], wA[12 + k0]};
        #pragma unroll
        for (int rt = 0; rt < 4; rt++) {
            bf16x8 a = *(const bf16x8*)(epv[rt] + k0 * 32);
            mfma4T(a, wf, acc[rt]);
        }
    }
    store_T<4, true>(t1, rbase, wc, lane, acc, b1);
    __syncthreads();                                   // bar1
    zero_accs<4>(acc);
    gemm_reg_T<4>(t1, rbase, wB, lane, acc);
    load_w16(W3f, wc, lane, wB);                       // W3 in flight across store+bar2
    store_T<4, true>(t2, rbase, wc, lane, acc, b2);
    __syncthreads();                                   // bar2
    // prefetch epilogue e_old now -> latency hides under the L3 gemm + store
    bf16x8 eold[8];
    #pragma unroll
    for (int p = 0; p < 8; p++) {
        const int lrow = rbase + p * 8 + (lane >> 3);
        const int col = wc * 64 + (lane & 7) * 8;
        eold[p] = *(const bf16x8*)(e + (size_t)(row0 + lrow) * HD + col);
    }
    zero_accs<4>(acc);
    gemm_reg_T<4>(t2, rbase, wB, lane, acc);
    store_T<4, false>(t1, rbase, wc, lane, acc, b3);   // t1 reads done pre-bar2
    // wave-private coalesced epilogue with prefetched residual
    #pragma unroll
    for (int p = 0; p < 8; p++) {
        const int lrow = rbase + p * 8 + (lane >> 3);
        const int col = wc * 64 + (lane & 7) * 8;
        bf16x8 tv = *(const bf16x8*)(t1 + lrow * 136 + col);
        bf16x8 res;
        #pragma unroll
        for (int k = 0; k < 8; k++)
            res[k] = (short)f2b(b2f((u16)tv[k]) + b2f((u16)eold[p][k]));
        *(bf16x8*)(e + (size_t)(row0 + lrow) * HD + col) = res;
    }
}

// ---------------- node step (BM=64, 4 waves, RT=2) + fused next-step P compute ----------------
__global__ __launch_bounds__(256, 3) void node_mfma(
    u16* __restrict__ h, const u16* __restrict__ e, const int* __restrict__ offsets,
    const u16* __restrict__ W1f, const float* __restrict__ b1,
    const u16* __restrict__ W2f, const float* __restrict__ b2,
    const u16* __restrict__ W3f, const float* __restrict__ b3,
    const u16* __restrict__ W1sNx, const u16* __restrict__ W1dNx,
    u16* __restrict__ Ps, u16* __restrict__ Pd) {
    __shared__ u16 tb[64 * 136];
    __shared__ u16 aggT[64 * 136];
    const int tid = threadIdx.x;
    const int lane = tid & 63, w = tid >> 6, wr = w >> 1, wc = w & 1;
    const int cl = lane & 15, q8 = (lane >> 4) * 8;
    const int row0 = blockIdx.x * 64;
    const int rbase = wr * 32;

    {   // aggregation: 4 thr/row x 32 ch; j-unrolled for ILP
        const int r = tid >> 2, sgi = tid & 3;
        const int node = row0 + r;
        const int beg = offsets[node], end = offsets[node + 1];
        float s[32];
        #pragma unroll
        for (int k = 0; k < 32; k++) s[k] = 0.0f;
        const u16* ebase = e + sgi * 32;
        int j = beg;
        for (; j + 2 <= end; j += 2) {
            const bf16x8* e0 = (const bf16x8*)(ebase + (size_t)j * HD);
            const bf16x8* e1 = (const bf16x8*)(ebase + (size_t)(j + 1) * HD);
            bf16x8 v0 = e0[0], v1 = e0[1], v2 = e0[2], v3 = e0[3];
            bf16x8 u0 = e1[0], u1 = e1[1], u2 = e1[2], u3 = e1[3];
            #pragma unroll
            for (int k = 0; k < 8; k++) {
                s[k]      += b2f((u16)v0[k]) + b2f((u16)u0[k]);
                s[8 + k]  += b2f((u16)v1[k]) + b2f((u16)u1[k]);
                s[16 + k] += b2f((u16)v2[k]) + b2f((u16)u2[k]);
                s[24 + k] += b2f((u16)v3[k]) + b2f((u16)u3[k]);
            }
        }
        if (j < end) {
            const bf16x8* e0 = (const bf16x8*)(ebase + (size_t)j * HD);
            bf16x8 v0 = e0[0], v1 = e0[1], v2 = e0[2], v3 = e0[3];
            #pragma unroll
            for (int k = 0; k < 8; k++) {
                s[k]      += b2f((u16)v0[k]);
                s[8 + k]  += b2f((u16)v1[k]);
                s[16 + k] += b2f((u16)v2[k]);
                s[24 + k] += b2f((u16)v3[k]);
            }
        }
        #pragma unroll
        for (int q = 0; q < 4; q++) {
            bf16x8 o;
            #pragma unroll
            for (int k = 0; k < 8; k++) o[k] = (short)f2b(s[q * 8 + k]);
            *(bf16x8*)(aggT + r * 136 + sgi * 32 + q * 8) = o;
        }
    }
    __syncthreads();                                   // bar1: aggT visible

    f32x4 acc[2][4];
    zero_accs<2>(acc);
    const u16* b1p = W1f + (size_t)(wc * 32) * 512 + lane * 8;  // KC1=8
    const u16* hp[2];
    #pragma unroll
    for (int rt = 0; rt < 2; rt++)
        hp[rt] = h + (size_t)(row0 + rbase + rt * 16 + cl) * HD + q8;
    #pragma unroll
    for (int k0 = 0; k0 < 4; k0++) {   // h section (global)
        bf16x8 wf[4];
        #pragma unroll
        for (int ct = 0; ct < 4; ct++) wf[ct] = *(const bf16x8*)(b1p + (ct * 8 + k0) * 512);
        #pragma unroll
        for (int rt = 0; rt < 2; rt++) {
            bf16x8 a = *(const bf16x8*)(hp[rt] + k0 * 32);
            mfma4T(a, wf, acc[rt]);
        }
    }
    #pragma unroll
    for (int k0 = 0; k0 < 4; k0++) {   // agg section (LDS)
        bf16x8 wf[4];
        #pragma unroll
        for (int ct = 0; ct < 4; ct++) wf[ct] = *(const bf16x8*)(b1p + (ct * 8 + 4 + k0) * 512);
        #pragma unroll
        for (int rt = 0; rt < 2; rt++) {
            bf16x8 a = *(const bf16x8*)(aggT + (rbase + rt * 16 + cl) * 136 + k0 * 32 + q8);
            mfma4T(a, wf, acc[rt]);
        }
    }
    store_T<2, true>(tb, rbase, wc, lane, acc, b1);
    __syncthreads();                                   // bar2
    zero_accs<2>(acc);
    gemm_lds_T<4, 2>(tb, rbase, W2f, wc, lane, acc);
    store_T<2, true>(aggT, rbase, wc, lane, acc, b2);  // aggT safe after bar2
    __syncthreads();                                   // bar3
    // prefetch epilogue h_old -> latency hides under the L3 gemm + store
    bf16x8 hold[4];
    #pragma unroll
    for (int p = 0; p < 4; p++) {
        const int lrow = rbase + p * 8 + (lane >> 3);
        const int col = wc * 64 + (lane & 7) * 8;
        hold[p] = *(const bf16x8*)(h + (size_t)(row0 + lrow) * HD + col);
    }
    zero_accs<2>(acc);
    gemm_lds_T<4, 2>(aggT, rbase, W3f, wc, lane, acc);
    store_T<2, false>(tb, rbase, wc, lane, acc, b3);   // tb safe after bar3
    // epilogue: residual, write h_new to global AND back into tb (same wave region)
    #pragma unroll
    for (int p = 0; p < 4; p++) {
        const int lrow = rbase + p * 8 + (lane >> 3);
        const int col = wc * 64 + (lane & 7) * 8;
        bf16x8 tv = *(const bf16x8*)(tb + lrow * 136 + col);
        bf16x8 res;
        #pragma unroll
        for (int k = 0; k < 8; k++)
            res[k] = (short)f2b(b2f((u16)tv[k]) + b2f((u16)hold[p][k]));
        *(bf16x8*)(h + (size_t)(row0 + lrow) * HD + col) = res;
        *(bf16x8*)(tb + lrow * 136 + col) = res;
    }
    if (W1sNx) {   // fused P precompute for the NEXT step (tb now holds h_new)
        __syncthreads();                               // bar4: tb h_new + aggT free
        bf16x8 wB[16];
        load_w16(W1sNx, wc, lane, wB);
        f32x4 pac[2][4];
        zero_accs<2>(pac);
        gemm_reg_T<2>(tb, rbase, wB, lane, pac);
        store_T_perm<2>(aggT, rbase, wc, lane, pac);
        epi_plain<2>(aggT, Ps, row0, rbase, NNDP, wc, lane);
        load_w16(W1dNx, wc, lane, wB);
        zero_accs<2>(pac);
        gemm_reg_T<2>(tb, rbase, wB, lane, pac);
        store_T_perm<2>(aggT, rbase, wc, lane, pac);
        epi_plain<2>(aggT, Pd, row0, rbase, NNDP, wc, lane);
    }
}

// ---------------- decoder: h -> MLP(H,H,OUT=2) fp32 out ----------------
__global__ __launch_bounds__(256, 4) void dec_mfma(
    const u16* __restrict__ h,
    const u16* __restrict__ W1f, const float* __restrict__ b1,
    const u16* __restrict__ W2f, const float* __restrict__ b2,
    const float* __restrict__ W3, const float* __restrict__ b3,
    float* __restrict__ out) {
    __shared__ u16 t1[32 * 136];
    __shared__ u16 t2[32 * 136];
    const int tid = threadIdx.x;
    const int lane = tid & 63, w = tid >> 6, wr = w >> 1, wc = w & 1;
    const int cl = lane & 15, q8 = (lane >> 4) * 8;
    const int row0 = blockIdx.x * 32;
    const int rbase = wr * 16;
    const u16* hp = h + (size_t)(row0 + rbase + cl) * HD + q8;

    f32x4 acc[1][4];
    zero_accs<1>(acc);
    const u16* b1p = W1f + (size_t)(wc * 16) * 512 + lane * 8;  // KC=4
    #pragma unroll
    for (int k0 = 0; k0 < 4; k0++) {
        bf16x8 wf[4];
        #pragma unroll
        for (int ct = 0; ct < 4; ct++) wf[ct] = *(const bf16x8*)(b1p + (ct * 4 + k0) * 512);
        bf16x8 a = *(const bf16x8*)(hp + k0 * 32);
        mfma4T(a, wf, acc[0]);
    }
    store_T<1, true>(t1, rbase, wc, lane, acc, b1);
    __syncthreads();
    zero_accs<1>(acc);
    gemm_lds_T<4, 1>(t1, rbase, W2f, wc, lane, acc);
    store_T<1, true>(t2, rbase, wc, lane, acc, b2);
    __syncthreads();
    if (tid < 64) {
        const int rr = tid >> 1, o = tid & 1;
        const int grow = row0 + rr;
        if (grow < NND) {
            float a = b3[o];
            for (int k = 0; k < HD; k++) a += b2f(t2[rr * 136 + k]) * W3[k * 2 + o];
            out[(size_t)grow * 2 + o] = a;
        }
    }
}

extern "C" void kernel_launch(void* const* d_in, const int* in_sizes, int n_in,
                              void* d_out, int out_size, void* d_ws, size_t ws_size,
                              hipStream_t stream) {
    (void)in_sizes; (void)n_in; (void)out_size; (void)ws_size;
    const float* x    = (const float*)d_in[0];
    const float* eatt = (const float*)d_in[1];
    const int*   eidx = (const int*)d_in[2];
    const float *neW1 = (const float*)d_in[3],  *neb1 = (const float*)d_in[4];
    const float *neW2 = (const float*)d_in[5],  *neb2 = (const float*)d_in[6];
    const float *neW3 = (const float*)d_in[7],  *neb3 = (const float*)d_in[8];
    const float *eeW1 = (const float*)d_in[9],  *eeb1 = (const float*)d_in[10];
    const float *eeW2 = (const float*)d_in[11], *eeb2 = (const float*)d_in[12];
    const float *eeW3 = (const float*)d_in[13], *eeb3 = (const float*)d_in[14];
    const float *peW1 = (const float*)d_in[15], *peb1 = (const float*)d_in[16];
    const float *peW2 = (const float*)d_in[17], *peb2 = (const float*)d_in[18];
    const float *peW3 = (const float*)d_in[19], *peb3 = (const float*)d_in[20];
    const float *pnW1 = (const float*)d_in[21], *pnb1 = (const float*)d_in[22];
    const float *pnW2 = (const float*)d_in[23], *pnb2 = (const float*)d_in[24];
    const float *pnW3 = (const float*)d_in[25], *pnb3 = (const float*)d_in[26];
    const float *ndW1 = (const float*)d_in[27], *ndb1 = (const float*)d_in[28];
    const float *ndW2 = (const float*)d_in[29], *ndb2 = (const float*)d_in[30];
    const float *ndW3 = (const float*)d_in[31], *ndb3 = (const float*)d_in[32];

    char* ws = (char*)d_ws;
    u16*   h       = (u16*)ws;                      // [NNDP][HD] bf16
    u16*   e       = (u16*)(ws + 12812288);         // [NED][HD] bf16 (dst-sorted)
    int*   bsum    = (int*)(ws + 115212288);
    int*   bbase   = (int*)(ws + 115213312);
    int*   counts  = (int*)(ws + 115245056);
    int*   cursors = (int*)(ws + 115445248);
    int*   offsets = (int*)(ws + 115645440);        // [NNDP+1]
    int4*  epk     = (int4*)(ws + 115845760);       // [NED] {src,dst,perm,0}
    u16*   Ps      = (u16*)(ws + 122245760);        // [NNDP][HD] bf16 (permuted cols)
    u16*   Pd      = (u16*)(ws + 135058048);        // [NNDP][HD] bf16 (permuted cols)
    u16*   wts     = (u16*)(ws + 147870336);

    u16* p = wts;
    u16 *neW1t = p; p += 128 * 32;
    u16 *neW2t = p; p += 128 * 128;
    u16 *neW3t = p; p += 128 * 128;
    u16 *eeW1t = p; p += 128 * 32;
    u16 *eeW2t = p; p += 128 * 128;
    u16 *eeW3t = p; p += 128 * 128;
    u16 *peW1sF[NSTEP], *peW1dF[NSTEP], *peW1eF[NSTEP], *peW2t[NSTEP], *peW3t[NSTEP];
    u16 *pnW1t[NSTEP], *pnW2t[NSTEP], *pnW3t[NSTEP];
    for (int t = 0; t < NSTEP; t++) {
        peW1sF[t] = p; p += 128 * 128;
        peW1dF[t] = p; p += 128 * 128;
        peW1eF[t] = p; p += 128 * 128;
        peW2t[t]  = p; p += 128 * 128;
        peW3t[t]  = p; p += 128 * 128;
    }
    for (int t = 0; t < NSTEP; t++) {
        pnW1t[t] = p; p += 128 * 256;
        pnW2t[t] = p; p += 128 * 128;
        pnW3t[t] = p; p += 128 * 128;
    }
    u16 *ndW1t = p; p += 128 * 128;
    u16 *ndW2t = p; p += 128 * 128;

    hipMemsetAsync(counts, 0, NNDP * sizeof(int), stream);
    count_kernel<<<(NED + 255) / 256, 256, 0, stream>>>(eidx, counts);
    bsum_kernel<<<NSB, 256, 0, stream>>>(counts, bsum);
    bscan_kernel<<<1, 256, 0, stream>>>(bsum, bbase, offsets);
    blocal_kernel<<<NSB, 256, 0, stream>>>(counts, bbase, offsets, cursors);
    fill_kernel<<<(NED + 255) / 256, 256, 0, stream>>>(eidx, cursors, epk);

    WPall wa;
    int wn = 0;
    auto ADD = [&](const float* s, u16* d, int K, int Kp) {
        wa.s[wn] = s; wa.d[wn] = d; wa.K[wn] = K; wa.Kp[wn] = Kp; wn++;
    };
    ADD(neW1, neW1t, 4, 32);
    ADD(neW2, neW2t, 128, 128);
    ADD(neW3, neW3t, 128, 128);
    ADD(eeW1, eeW1t, 3, 32);
    ADD(eeW2, eeW2t, 128, 128);
    ADD(eeW3, eeW3t, 128, 128);
    for (int t = 0; t < NSTEP; t++) {
        const float* base = peW1 + (size_t)t * 384 * 128;
        ADD(base,             peW1sF[t], 128, 128);   // rows 0..127   (h[src])
        ADD(base + 128 * 128, peW1dF[t], 128, 128);   // rows 128..255 (h[dst])
        ADD(base + 256 * 128, peW1eF[t], 128, 128);   // rows 256..383 (e)
        ADD(peW2 + (size_t)t * 128 * 128, peW2t[t], 128, 128);
        ADD(peW3 + (size_t)t * 128 * 128, peW3t[t], 128, 128);
        ADD(pnW1 + (size_t)t * 256 * 128, pnW1t[t], 256, 256);
        ADD(pnW2 + (size_t)t * 128 * 128, pnW2t[t], 128, 128);
        ADD(pnW3 + (size_t)t * 128 * 128, pnW3t[t], 128, 128);
    }
    ADD(ndW1, ndW1t, 128, 128);
    ADD(ndW2, ndW2t, 128, 128);
    wprep_all<<<dim3(128, NWP), 256, 0, stream>>>(wa);

    enc_mfma<<<NNDP / 64, 256, 0, stream>>>(x, 4, NND, nullptr,
                                            neW1t, neb1, neW2t, neb2, neW3t, neb3, h);
    enc_mfma<<<NED / 64, 256, 0, stream>>>(eatt, 3, NED, epk,
                                           eeW1t, eeb1, eeW2t, eeb2, eeW3t, eeb3, e);
    pnode_mfma<<<NNDP / 64, 256, 0, stream>>>(h, peW1sF[0], peW1dF[0], Ps, Pd);

    for (int t = 0; t < NSTEP; t++) {
        edge_mfma<<<NED / 128, 256, 0, stream>>>(
            e, epk, Ps, Pd,
            peW1eF[t], peb1 + (size_t)t * HD,
            peW2t[t],  peb2 + (size_t)t * HD,
            peW3t[t],  peb3 + (size_t)t * HD);
        const bool last = (t + 1 == NSTEP);
        node_mfma<<<NNDP / 64, 256, 0, stream>>>(
            h, e, offsets,
            pnW1t[t], pnb1 + (size_t)t * HD,
            pnW2t[t], pnb2 + (size_t)t * HD,
            pnW3t[t], pnb3 + (size_t)t * HD,
            last ? nullptr : peW1sF[t + 1],
            last ? nullptr : peW1dF[t + 1],
            Ps, Pd);
    }
    dec_mfma<<<NNDP / 32, 256, 0, stream>>>(h, ndW1t, ndb1, ndW2t, ndb2, ndW3, ndb3, (float*)d_out);
}